// Round 17
// baseline (672.229 us; speedup 1.0000x reference)
//
#include <hip/hip_runtime.h>
#include <hip/hip_bf16.h>
#include <math.h>

#define RTOT 8192      // B*T
#define TSEQ 2048

typedef __attribute__((ext_vector_type(8))) short short8;
typedef __attribute__((ext_vector_type(4))) float f32x4;
typedef unsigned short u16;
typedef unsigned int u32;

union U16x8 { uint4 v; u16 s[8]; };

__device__ __forceinline__ float sigmoidf_(float x) { return 1.f / (1.f + expf(-x)); }
__device__ __forceinline__ float bf2f(u16 v) { u32 u = ((u32)v) << 16; float f; __builtin_memcpy(&f, &u, 4); return f; }
__device__ __forceinline__ u16 f2bf(float f) {
  u32 u; __builtin_memcpy(&u, &f, 4);
  u32 r = (u + 0x7FFFu + ((u >> 16) & 1u)) >> 16;
  return (u16)r;
}
// split f32 -> hi bf16 + lo bf16 (residual)
__device__ __forceinline__ void split2(float x, u16& h, u16& l) {
  u16 hh = f2bf(x);
  float hf = bf2f(hh);
  h = hh; l = f2bf(x - hf);
}

typedef const void __attribute__((address_space(1))) gvoid_t;
typedef void __attribute__((address_space(3))) lvoid_t;
__device__ __forceinline__ void gload_lds16(const void* g, void* l) {
  __builtin_amdgcn_global_load_lds((gvoid_t*)g, (lvoid_t*)l, 16, 0, 0);
}

// XCD-chunked bijective block remap (nwg % 8 == 0 required)
__device__ __forceinline__ void xcd_remap(int& bx, int& by) {
  int gx = gridDim.x, nwg = gx * gridDim.y;
  int bid = blockIdx.y * gx + blockIdx.x;
  int cpx = nwg >> 3;
  int swz = (bid & 7) * cpx + (bid >> 3);
  bx = swz % gx; by = swz / gx;
}

// ======= 256^2-tile 4-phase pipelined split-bf16 GEMM (QKV) — r12 proven ====
__global__ __launch_bounds__(512) void gemm_sp_big(const u16* __restrict__ Ah, const u16* __restrict__ Al,
                                                   const u16* __restrict__ Bh, const u16* __restrict__ Bl,
                                                   float* __restrict__ Cf,
                                                   int M, int N, int K) {
  __shared__ u16 lds[2][4][256 * 32];   // [buf][Ah,Al,Bh,Bl][row][k]
  int bx, by; xcd_remap(bx, by);
  const int tid = threadIdx.x;
  const int l = tid & 63, w = tid >> 6;
  const int wr = w >> 2, wc = w & 3;           // 2 x 4 wave grid
  const int m0 = by * 256, n0 = bx * 256;
  const int fr = l & 15, fq = l >> 4;
  const int koff = 8 * (fq ^ (fr & 3));        // swizzled read granule
  const int srow = tid >> 2;
  const int scol = ((tid & 3) ^ (srow & 3)) * 8;
  const u16* gA_h = Ah + (size_t)(m0 + srow) * K + scol;
  const u16* gA_l = Al + (size_t)(m0 + srow) * K + scol;
  const u16* gB_h = Bh + (size_t)(n0 + srow) * K + scol;
  const u16* gB_l = Bl + (size_t)(n0 + srow) * K + scol;
  const int lo = srow * 32 + (tid & 3) * 8;    // linear LDS dest
  const int NT = K >> 5;

#define STG(buf, mat, src, t)                                 \
  do {                                                        \
    const int k0_ = (t) << 5;                                 \
    gload_lds16(src + k0_, &lds[buf][mat][lo]);               \
    gload_lds16(src + 128 * K + k0_, &lds[buf][mat][lo + 4096]); \
  } while (0)

#define MFMA_PAIR(mi, a_h, a_l)                                                        \
  do {                                                                                 \
    _Pragma("unroll")                                                                  \
    for (int n = 0; n < 4; ++n) {                                                      \
      acc[mi][n] = __builtin_amdgcn_mfma_f32_16x16x32_bf16(a_h, bh8[n], acc[mi][n], 0, 0, 0); \
      acc[mi][n] = __builtin_amdgcn_mfma_f32_16x16x32_bf16(a_h, bl8[n], acc[mi][n], 0, 0, 0); \
      acc[mi][n] = __builtin_amdgcn_mfma_f32_16x16x32_bf16(a_l, bh8[n], acc[mi][n], 0, 0, 0); \
    }                                                                                  \
  } while (0)

  f32x4 acc[8][4] = {};
  STG(0, 0, gA_h, 0); STG(0, 1, gA_l, 0); STG(0, 2, gB_h, 0); STG(0, 3, gB_l, 0);
  asm volatile("s_waitcnt vmcnt(0)" ::: "memory");
  __builtin_amdgcn_s_barrier();

  for (int t = 0; t < NT; ++t) {
    const int c = t & 1, o = c ^ 1;
    const bool pf = (t + 1 < NT);
    short8 bh8[4], bl8[4];
    // P0: B-frags + A m=0,1 | stage B(t+1)
    {
#pragma unroll
      for (int n = 0; n < 4; ++n) {
        bh8[n] = *(const short8*)&lds[c][2][(wc * 64 + n * 16 + fr) * 32 + koff];
        bl8[n] = *(const short8*)&lds[c][3][(wc * 64 + n * 16 + fr) * 32 + koff];
      }
      short8 a0h = *(const short8*)&lds[c][0][(wr * 128 + 0 * 16 + fr) * 32 + koff];
      short8 a1h = *(const short8*)&lds[c][0][(wr * 128 + 1 * 16 + fr) * 32 + koff];
      short8 a0l = *(const short8*)&lds[c][1][(wr * 128 + 0 * 16 + fr) * 32 + koff];
      short8 a1l = *(const short8*)&lds[c][1][(wr * 128 + 1 * 16 + fr) * 32 + koff];
      if (pf) { STG(o, 2, gB_h, t + 1); STG(o, 3, gB_l, t + 1); }
      __builtin_amdgcn_s_barrier();
      asm volatile("s_waitcnt lgkmcnt(0)" ::: "memory");
      __builtin_amdgcn_s_setprio(1);
      MFMA_PAIR(0, a0h, a0l);
      MFMA_PAIR(1, a1h, a1l);
      __builtin_amdgcn_s_setprio(0);
      __builtin_amdgcn_s_barrier();
    }
    // P1: A m=2,3 | stage A(t+1)
    {
      short8 a0h = *(const short8*)&lds[c][0][(wr * 128 + 2 * 16 + fr) * 32 + koff];
      short8 a1h = *(const short8*)&lds[c][0][(wr * 128 + 3 * 16 + fr) * 32 + koff];
      short8 a0l = *(const short8*)&lds[c][1][(wr * 128 + 2 * 16 + fr) * 32 + koff];
      short8 a1l = *(const short8*)&lds[c][1][(wr * 128 + 3 * 16 + fr) * 32 + koff];
      if (pf) { STG(o, 0, gA_h, t + 1); STG(o, 1, gA_l, t + 1); }
      __builtin_amdgcn_s_barrier();
      asm volatile("s_waitcnt lgkmcnt(0)" ::: "memory");
      __builtin_amdgcn_s_setprio(1);
      MFMA_PAIR(2, a0h, a0l);
      MFMA_PAIR(3, a1h, a1l);
      __builtin_amdgcn_s_setprio(0);
      __builtin_amdgcn_s_barrier();
    }
    // P2: A m=4,5
    {
      short8 a0h = *(const short8*)&lds[c][0][(wr * 128 + 4 * 16 + fr) * 32 + koff];
      short8 a1h = *(const short8*)&lds[c][0][(wr * 128 + 5 * 16 + fr) * 32 + koff];
      short8 a0l = *(const short8*)&lds[c][1][(wr * 128 + 4 * 16 + fr) * 32 + koff];
      short8 a1l = *(const short8*)&lds[c][1][(wr * 128 + 5 * 16 + fr) * 32 + koff];
      __builtin_amdgcn_s_barrier();
      asm volatile("s_waitcnt lgkmcnt(0)" ::: "memory");
      __builtin_amdgcn_s_setprio(1);
      MFMA_PAIR(4, a0h, a0l);
      MFMA_PAIR(5, a1h, a1l);
      __builtin_amdgcn_s_setprio(0);
      __builtin_amdgcn_s_barrier();
    }
    // P3: A m=6,7 | drain t+1 loads
    {
      short8 a0h = *(const short8*)&lds[c][0][(wr * 128 + 6 * 16 + fr) * 32 + koff];
      short8 a1h = *(const short8*)&lds[c][0][(wr * 128 + 7 * 16 + fr) * 32 + koff];
      short8 a0l = *(const short8*)&lds[c][1][(wr * 128 + 6 * 16 + fr) * 32 + koff];
      short8 a1l = *(const short8*)&lds[c][1][(wr * 128 + 7 * 16 + fr) * 32 + koff];
      __builtin_amdgcn_s_barrier();
      asm volatile("s_waitcnt lgkmcnt(0)" ::: "memory");
      __builtin_amdgcn_s_setprio(1);
      MFMA_PAIR(6, a0h, a0l);
      MFMA_PAIR(7, a1h, a1l);
      __builtin_amdgcn_s_setprio(0);
      if (pf) asm volatile("s_waitcnt vmcnt(0)" ::: "memory");
      __builtin_amdgcn_s_barrier();
    }
  }
#undef STG
#undef MFMA_PAIR
#pragma unroll
  for (int m = 0; m < 8; ++m)
#pragma unroll
    for (int n = 0; n < 4; ++n)
#pragma unroll
      for (int r = 0; r < 4; ++r)
        Cf[(size_t)(m0 + wr * 128 + m * 16 + 4 * fq + r) * N + (n0 + wc * 64 + n * 16 + fr)] = acc[m][n][r];
}

// ======= BM=128/BN=256 2-phase pipelined split-bf16 GEMM (Wo/Wg) ===========
// EPI 1: split pair out.  EPI 3: Cf = (Pinh+Pinl) * sigmoid(acc)
template<int EPI>
__global__ __launch_bounds__(512) void gemm_sp_mid(const u16* __restrict__ Ah, const u16* __restrict__ Al,
                                                   const u16* __restrict__ Bh, const u16* __restrict__ Bl,
                                                   float* __restrict__ Cf, u16* __restrict__ Ph,
                                                   u16* __restrict__ Pl, const u16* __restrict__ Pinh,
                                                   const u16* __restrict__ Pinl,
                                                   int M, int N, int K) {
  __shared__ u16 lds[2][24576];
  int bx, by; xcd_remap(bx, by);
  const int tid = threadIdx.x;
  const int l = tid & 63, w = tid >> 6;
  const int wr = w >> 2, wc = w & 3;           // 2M x 4N
  const int m0 = by * 128, n0 = bx * 256;
  const int fr = l & 15, fq = l >> 4;
  const int koff = 8 * (fq ^ (fr & 3));
  const int srow = tid >> 2;                   // 0..127
  const int scol = ((tid & 3) ^ (srow & 3)) * 8;
  const u16* gA_h = Ah + (size_t)(m0 + srow) * K + scol;
  const u16* gA_l = Al + (size_t)(m0 + srow) * K + scol;
  const u16* gB_h = Bh + (size_t)(n0 + srow) * K + scol;
  const u16* gB_l = Bl + (size_t)(n0 + srow) * K + scol;
  const int lo = srow * 32 + (tid & 3) * 8;
  const int NT = K >> 5;

#define STGA(buf, t)                                              \
  do {                                                            \
    const int k0_ = (t) << 5;                                     \
    gload_lds16(gA_h + k0_, &lds[buf][lo]);                       \
    gload_lds16(gA_l + k0_, &lds[buf][4096 + lo]);                \
  } while (0)
#define STGB(buf, t)                                              \
  do {                                                            \
    const int k0_ = (t) << 5;                                     \
    gload_lds16(gB_h + k0_, &lds[buf][8192 + lo]);                \
    gload_lds16(gB_h + 128 * K + k0_, &lds[buf][8192 + 4096 + lo]); \
    gload_lds16(gB_l + k0_, &lds[buf][16384 + lo]);               \
    gload_lds16(gB_l + 128 * K + k0_, &lds[buf][16384 + 4096 + lo]); \
  } while (0)
#define MFMA_PAIR(mi, a_h, a_l)                                                        \
  do {                                                                                 \
    _Pragma("unroll")                                                                  \
    for (int n = 0; n < 4; ++n) {                                                      \
      acc[mi][n] = __builtin_amdgcn_mfma_f32_16x16x32_bf16(a_h, bh8[n], acc[mi][n], 0, 0, 0); \
      acc[mi][n] = __builtin_amdgcn_mfma_f32_16x16x32_bf16(a_h, bl8[n], acc[mi][n], 0, 0, 0); \
      acc[mi][n] = __builtin_amdgcn_mfma_f32_16x16x32_bf16(a_l, bh8[n], acc[mi][n], 0, 0, 0); \
    }                                                                                  \
  } while (0)

  f32x4 acc[4][4] = {};
  STGA(0, 0); STGB(0, 0);
  asm volatile("s_waitcnt vmcnt(0)" ::: "memory");
  __builtin_amdgcn_s_barrier();

  for (int t = 0; t < NT; ++t) {
    const int c = t & 1, o = c ^ 1;
    const bool pf = (t + 1 < NT);
    short8 bh8[4], bl8[4];
    // P0: B-frags + A m=0,1 | stage B(t+1)
    {
#pragma unroll
      for (int n = 0; n < 4; ++n) {
        bh8[n] = *(const short8*)&lds[c][8192 + (wc * 64 + n * 16 + fr) * 32 + koff];
        bl8[n] = *(const short8*)&lds[c][16384 + (wc * 64 + n * 16 + fr) * 32 + koff];
      }
      short8 a0h = *(const short8*)&lds[c][(wr * 64 + 0 * 16 + fr) * 32 + koff];
      short8 a1h = *(const short8*)&lds[c][(wr * 64 + 1 * 16 + fr) * 32 + koff];
      short8 a0l = *(const short8*)&lds[c][4096 + (wr * 64 + 0 * 16 + fr) * 32 + koff];
      short8 a1l = *(const short8*)&lds[c][4096 + (wr * 64 + 1 * 16 + fr) * 32 + koff];
      if (pf) STGB(o, t + 1);
      __builtin_amdgcn_s_barrier();
      asm volatile("s_waitcnt lgkmcnt(0)" ::: "memory");
      __builtin_amdgcn_s_setprio(1);
      MFMA_PAIR(0, a0h, a0l);
      MFMA_PAIR(1, a1h, a1l);
      __builtin_amdgcn_s_setprio(0);
      __builtin_amdgcn_s_barrier();
    }
    // P1: A m=2,3 | stage A(t+1) | drain
    {
      short8 a0h = *(const short8*)&lds[c][(wr * 64 + 2 * 16 + fr) * 32 + koff];
      short8 a1h = *(const short8*)&lds[c][(wr * 64 + 3 * 16 + fr) * 32 + koff];
      short8 a0l = *(const short8*)&lds[c][4096 + (wr * 64 + 2 * 16 + fr) * 32 + koff];
      short8 a1l = *(const short8*)&lds[c][4096 + (wr * 64 + 3 * 16 + fr) * 32 + koff];
      if (pf) STGA(o, t + 1);
      __builtin_amdgcn_s_barrier();
      asm volatile("s_waitcnt lgkmcnt(0)" ::: "memory");
      __builtin_amdgcn_s_setprio(1);
      MFMA_PAIR(2, a0h, a0l);
      MFMA_PAIR(3, a1h, a1l);
      __builtin_amdgcn_s_setprio(0);
      if (pf) asm volatile("s_waitcnt vmcnt(0)" ::: "memory");
      __builtin_amdgcn_s_barrier();
    }
  }
#undef STGA
#undef STGB
#undef MFMA_PAIR
  const int rbase = m0 + wr * 64 + 4 * fq;
  const int cbase = n0 + wc * 64 + fr;
#pragma unroll
  for (int m = 0; m < 4; ++m)
#pragma unroll
    for (int n = 0; n < 4; ++n)
#pragma unroll
      for (int r = 0; r < 4; ++r) {
        size_t idx = (size_t)(rbase + m * 16 + r) * N + (cbase + n * 16);
        float v = acc[m][n][r];
        if (EPI == 1) {
          u16 h, lo2; split2(v, h, lo2);
          Ph[idx] = h; Pl[idx] = lo2;
        } else {
          float pin = bf2f(Pinh[idx]) + bf2f(Pinl[idx]);
          Cf[idx] = pin * sigmoidf_(v);
        }
      }
}

// ======= prep: x cast+split + gab (bid<8192) OR weight transcast (else) =====
__global__ __launch_bounds__(256) void prep_all(const float* __restrict__ x,
                                                u16* __restrict__ xh, u16* __restrict__ xl,
                                                const float* __restrict__ Wa,
                                                const float* __restrict__ Wb,
                                                float* __restrict__ gout,
                                                const float* __restrict__ Wq,
                                                const float* __restrict__ Wk,
                                                const float* __restrict__ Wv,
                                                const float* __restrict__ Wo,
                                                const float* __restrict__ Wg,
                                                u16* __restrict__ Wqkv_h, u16* __restrict__ Wqkv_l,
                                                u16* __restrict__ Wo_h, u16* __restrict__ Wo_l,
                                                u16* __restrict__ Wg_h, u16* __restrict__ Wg_l) {
  const int tid = threadIdx.x;
  const int gbid = blockIdx.x;
  if (gbid < 8192) {
    // --- castx_gab path ---
    __shared__ float xs[1024];
    __shared__ float partial[256];
    const size_t row = gbid;
    float4 v = *(const float4*)(x + row * 1024 + tid * 4);
    *(float4*)(&xs[tid * 4]) = v;
    ushort4 hh, ll;
    split2(v.x, hh.x, ll.x); split2(v.y, hh.y, ll.y);
    split2(v.z, hh.z, ll.z); split2(v.w, hh.w, ll.w);
    *(ushort4*)(xh + row * 1024 + tid * 4) = hh;
    *(ushort4*)(xl + row * 1024 + tid * 4) = ll;
    __syncthreads();
    const int h = tid & 31;
    const int seg = tid >> 5;
    const float* W = (h < 16) ? Wa : Wb;
    const int col = h & 15;
    float s = 0.f;
    const int k0 = seg * 128;
    for (int k = 0; k < 128; ++k) s = fmaf(xs[k0 + k], W[(size_t)(k0 + k) * 16 + col], s);
    partial[tid] = s;
    __syncthreads();
    if (tid < 32) {
      float t2 = 0.f;
#pragma unroll
      for (int j = 0; j < 8; ++j) t2 += partial[j * 32 + tid];
      partial[tid] = t2;
    }
    __syncthreads();
    if (tid < 16)
      gout[row * 16 + tid] = sigmoidf_(partial[tid]) * sigmoidf_(partial[tid + 16]);
  } else {
    // --- transcast path ---
    __shared__ float t[32][33];
    const int bid = gbid - 8192;
    const float* W; u16 *Th, *Tl; int K, N, lb;
    if (bid < 1024)      { W = Wq; Th = Wqkv_h;              Tl = Wqkv_l;              K = 1024; N = 1024; lb = bid; }
    else if (bid < 2048) { W = Wk; Th = Wqkv_h + 1024*1024;  Tl = Wqkv_l + 1024*1024;  K = 1024; N = 1024; lb = bid - 1024; }
    else if (bid < 4096) { W = Wv; Th = Wqkv_h + 2048*1024;  Tl = Wqkv_l + 2048*1024;  K = 1024; N = 2048; lb = bid - 2048; }
    else if (bid < 6144) { W = Wo; Th = Wo_h;                Tl = Wo_l;                K = 2048; N = 1024; lb = bid - 4096; }
    else                 { W = Wg; Th = Wg_h;                Tl = Wg_l;                K = 1024; N = 1024; lb = bid - 6144; }
    const int nx = N >> 5;
    const int n0 = (lb % nx) * 32, k0 = (lb / nx) * 32;
    const int c = tid & 31, rq = tid >> 5;
#pragma unroll
    for (int i = 0; i < 4; ++i) t[rq * 4 + i][c] = W[(size_t)(k0 + rq * 4 + i) * N + n0 + c];
    __syncthreads();
#pragma unroll
    for (int i = 0; i < 4; ++i) {
      float v = t[c][rq * 4 + i];
      u16 h, lo; split2(v, h, lo);
      size_t idx = (size_t)(n0 + rq * 4 + i) * K + k0 + c;
      Th[idx] = h; Tl[idx] = lo;
    }
  }
}

// ======= merged conv: zrms+conv+SiLU for q,k,v in ONE launch ================
// 8192 blocks x 1024 threads. Waves 0-3 = q, 4-7 = k, 8-15 = v (g-scaled).
// Per-section reductions use disjoint red slots in the same order as before
// => bitwise-identical to the split kernels.
__global__ __launch_bounds__(1024) void conv_all(const float* __restrict__ qkv,
                                                 const float* __restrict__ cq,
                                                 const float* __restrict__ ck,
                                                 const float* __restrict__ cv,
                                                 const float* __restrict__ gq,
                                                 const float* __restrict__ gk,
                                                 const float* __restrict__ gv,
                                                 const float* __restrict__ gab,
                                                 u16* __restrict__ q_h, u16* __restrict__ q_l,
                                                 u16* __restrict__ k_h, u16* __restrict__ k_l,
                                                 u16* __restrict__ vg_h, u16* __restrict__ vg_l) {
  __shared__ float redA[16 * 4];
  __shared__ float redB[16 * 4];
  const int tid = threadIdx.x;
  const int bid = blockIdx.x;
  const int row = ((bid & 7) << 10) + (bid >> 3);   // XCD-chunked
  const int t = row & (TSEQ - 1);
  const int lane = tid & 63, wid = tid >> 6;
  int c, C, colbase, jlo, jhi, sec;
  const float *w, *g;
  u16 *oh, *ol;
  if (tid < 256)      { sec = 0; c = tid * 4;         C = 1024; colbase = 0;    jlo = 0; jhi = 4;  w = cq; g = gq; oh = q_h;  ol = q_l; }
  else if (tid < 512) { sec = 1; c = (tid - 256) * 4; C = 1024; colbase = 1024; jlo = 4; jhi = 8;  w = ck; g = gk; oh = k_h;  ol = k_l; }
  else                { sec = 2; c = (tid - 512) * 4; C = 2048; colbase = 2048; jlo = 8; jhi = 16; w = cv; g = gv; oh = vg_h; ol = vg_l; }
  float4 xv[4];
  float psum[4];
#pragma unroll
  for (int d = 0; d < 4; ++d) {
    if (t - d >= 0) xv[d] = *(const float4*)(qkv + (size_t)(row - d) * 4096 + colbase + c);
    else { xv[d].x = 0.f; xv[d].y = 0.f; xv[d].z = 0.f; xv[d].w = 0.f; }
    psum[d] = xv[d].x + xv[d].y + xv[d].z + xv[d].w;
  }
#pragma unroll
  for (int d = 0; d < 4; ++d)
#pragma unroll
    for (int o = 32; o > 0; o >>= 1) psum[d] += __shfl_xor(psum[d], o, 64);
  if (lane == 0) {
    redA[wid * 4 + 0] = psum[0]; redA[wid * 4 + 1] = psum[1];
    redA[wid * 4 + 2] = psum[2]; redA[wid * 4 + 3] = psum[3];
  }
  __syncthreads();
  float mean[4];
#pragma unroll
  for (int d = 0; d < 4; ++d) {
    float s = 0.f;
    for (int j = jlo; j < jhi; ++j) s += redA[j * 4 + d];
    mean[d] = s * (1.f / C);
  }
  float psq[4];
#pragma unroll
  for (int d = 0; d < 4; ++d) {
    float a = xv[d].x - mean[d], b = xv[d].y - mean[d];
    float e = xv[d].z - mean[d], f = xv[d].w - mean[d];
    psq[d] = a * a + b * b + e * e + f * f;
  }
#pragma unroll
  for (int d = 0; d < 4; ++d)
#pragma unroll
    for (int o = 32; o > 0; o >>= 1) psq[d] += __shfl_xor(psq[d], o, 64);
  if (lane == 0) {
    redB[wid * 4 + 0] = psq[0]; redB[wid * 4 + 1] = psq[1];
    redB[wid * 4 + 2] = psq[2]; redB[wid * 4 + 3] = psq[3];
  }
  __syncthreads();
  float rstd[4];
#pragma unroll
  for (int d = 0; d < 4; ++d) {
    float s = 0.f;
    for (int j = jlo; j < jhi; ++j) s += redB[j * 4 + d];
    rstd[d] = rsqrtf(s * (1.f / C) + 1e-5f);
  }
  float4 g4 = *(const float4*)(g + c);
  float4 acc; acc.x = 0.f; acc.y = 0.f; acc.z = 0.f; acc.w = 0.f;
#pragma unroll
  for (int d = 0; d < 4; ++d) {
    if (t - d >= 0) {
      float4 wv = *(const float4*)(w + (size_t)(3 - d) * C + c);
      acc.x = fmaf((xv[d].x - mean[d]) * rstd[d] * g4.x, wv.x, acc.x);
      acc.y = fmaf((xv[d].y - mean[d]) * rstd[d] * g4.y, wv.y, acc.y);
      acc.z = fmaf((xv[d].z - mean[d]) * rstd[d] * g4.z, wv.z, acc.z);
      acc.w = fmaf((xv[d].w - mean[d]) * rstd[d] * g4.w, wv.w, acc.w);
    }
  }
  float a0 = acc.x * sigmoidf_(acc.x);
  float a1 = acc.y * sigmoidf_(acc.y);
  float a2 = acc.z * sigmoidf_(acc.z);
  float a3 = acc.w * sigmoidf_(acc.w);
  if (sec == 2) {
    float gv2 = gab[(size_t)row * 16 + (c >> 7)];
    a0 *= gv2; a1 *= gv2; a2 *= gv2; a3 *= gv2;
  }
  ushort4 hh, ll;
  split2(a0, hh.x, ll.x); split2(a1, hh.y, ll.y);
  split2(a2, hh.z, ll.z); split2(a3, hh.w, ll.w);
  *(ushort4*)(oh + (size_t)row * C + c) = hh;
  *(ushort4*)(ol + (size_t)row * C + c) = ll;
}

// ======= scan: exclusive chunk-prefix of Vg^T K, kd-split (512 blocks) ======
__global__ __launch_bounds__(256) void scan_kernel(const u16* __restrict__ kh,
                                                   const u16* __restrict__ kl,
                                                   const u16* __restrict__ vgh,
                                                   const u16* __restrict__ vgl,
                                                   u16* __restrict__ Sph,
                                                   u16* __restrict__ Spl) {
  __shared__ float Ks[64][36];
  __shared__ float Vs[64][36];
  const int tid = threadIdx.x;
  const int bid = blockIdx.x;
  const int kq = bid & 1, vq = (bid >> 1) & 3, h = (bid >> 3) & 15, b = bid >> 7;
  const size_t rb = (size_t)b * TSEQ;
  const int vd_t = tid >> 3, kd0 = (tid & 7) * 4;
  float S[4] = {};
  const int sr = tid >> 2;
  const int cc0 = (tid & 3) * 8;
  for (int c = 0; c < 32; ++c) {
    {
      size_t koffg = (rb + (size_t)c * 64 + sr) * 1024 + h * 64 + kq * 32 + cc0;
      U16x8 a0, b0;
      a0.v = *(const uint4*)(kh + koffg);
      b0.v = *(const uint4*)(kl + koffg);
#pragma unroll
      for (int j = 0; j < 8; ++j) Ks[sr][cc0 + j] = bf2f(a0.s[j]) + bf2f(b0.s[j]);
      size_t voffg = (rb + (size_t)c * 64 + sr) * 2048 + h * 128 + vq * 32 + cc0;
      U16x8 va, vb;
      va.v = *(const uint4*)(vgh + voffg);
      vb.v = *(const uint4*)(vgl + voffg);
#pragma unroll
      for (int j = 0; j < 8; ++j) Vs[sr][cc0 + j] = bf2f(va.s[j]) + bf2f(vb.s[j]);
    }
    {
      size_t spc = (((size_t)(b * 16 + h) * 32) + c) * 8192
                 + (size_t)(vq * 32 + vd_t) * 64 + kq * 32 + kd0;
      ushort4 h0, l0;
      split2(S[0], h0.x, l0.x); split2(S[1], h0.y, l0.y);
      split2(S[2], h0.z, l0.z); split2(S[3], h0.w, l0.w);
      *(ushort4*)(Sph + spc) = h0;
      *(ushort4*)(Spl + spc) = l0;
    }
    __syncthreads();
    for (int s = 0; s < 64; ++s) {
      float vv = Vs[s][vd_t];
      float kv[4];
      *(float4*)kv = *(const float4*)&Ks[s][kd0];
#pragma unroll
      for (int j = 0; j < 4; ++j) S[j] = fmaf(vv, kv[j], S[j]);
    }
    __syncthreads();
  }
}

// ======= pass2: O = mask(QK^T) Vg + Q Sp^T  (MFMA, split; proven) ===========
__global__ __launch_bounds__(256) void pass2_sp(const u16* __restrict__ qh,
                                                const u16* __restrict__ ql,
                                                const u16* __restrict__ kh,
                                                const u16* __restrict__ vgh,
                                                const u16* __restrict__ Sph,
                                                const u16* __restrict__ Spl,
                                                u16* __restrict__ oh,
                                                u16* __restrict__ ol) {
  __shared__ u16 Qsh[64 * 72];
  __shared__ u16 Qsl[64 * 72];
  __shared__ u16 Ksm[64 * 72];
  __shared__ u16 Am[64 * 72];
  __shared__ u16 Vth[128 * 72];
  const int tid = threadIdx.x;
  const int l = tid & 63, w = tid >> 6;
  const int bid = blockIdx.x;
  const int c = bid & 31, h = (bid >> 5) & 15, b = bid >> 9;
  const size_t rb = (size_t)b * TSEQ + c * 64;
  const int fr = l & 15, fq = l >> 4;
  {
    int r = tid >> 2, c0 = (tid & 3) * 16;
    size_t off = (rb + r) * 1024 + h * 64 + c0;
    *(uint4*)&Qsh[r * 72 + c0]     = *(const uint4*)(qh + off);
    *(uint4*)&Qsh[r * 72 + c0 + 8] = *(const uint4*)(qh + off + 8);
    *(uint4*)&Qsl[r * 72 + c0]     = *(const uint4*)(ql + off);
    *(uint4*)&Qsl[r * 72 + c0 + 8] = *(const uint4*)(ql + off + 8);
    *(uint4*)&Ksm[r * 72 + c0]     = *(const uint4*)(kh + off);
    *(uint4*)&Ksm[r * 72 + c0 + 8] = *(const uint4*)(kh + off + 8);
  }
  {
    int s = tid >> 2, vd0 = (tid & 3) * 32;
    size_t off = (rb + s) * 2048 + h * 128 + vd0;
#pragma unroll
    for (int m4 = 0; m4 < 4; ++m4) {
      U16x8 r_; r_.v = *(const uint4*)(vgh + off + m4 * 8);
#pragma unroll
      for (int j = 0; j < 8; ++j) Vth[(vd0 + m4 * 8 + j) * 72 + s] = r_.s[j];
    }
  }
  __syncthreads();
  short8 aqh[2], aql[2];
#pragma unroll
  for (int kk = 0; kk < 2; ++kk) {
    aqh[kk] = *(const short8*)&Qsh[(w * 16 + fr) * 72 + kk * 32 + 8 * fq];
    aql[kk] = *(const short8*)&Qsl[(w * 16 + fr) * 72 + kk * 32 + 8 * fq];
  }
  f32x4 accA[4] = {};
#pragma unroll
  for (int n = 0; n < 4; ++n)
#pragma unroll
    for (int kk = 0; kk < 2; ++kk) {
      short8 bk = *(const short8*)&Ksm[(n * 16 + fr) * 72 + kk * 32 + 8 * fq];
      accA[n] = __builtin_amdgcn_mfma_f32_16x16x32_bf16(aqh[kk], bk, accA[n], 0, 0, 0);
    }
#pragma unroll
  for (int n = 0; n < 4; ++n)
#pragma unroll
    for (int rr = 0; rr < 4; ++rr) {
      int tt = w * 16 + 4 * fq + rr;
      int s = n * 16 + fr;
      Am[tt * 72 + s] = f2bf((s <= tt) ? accA[n][rr] : 0.f);
    }
  __syncthreads();
  f32x4 acc[8] = {};
#pragma unroll
  for (int kk = 0; kk < 2; ++kk) {
    short8 aa = *(const short8*)&Am[(w * 16 + fr) * 72 + kk * 32 + 8 * fq];
#pragma unroll
    for (int n = 0; n < 8; ++n) {
      short8 bv = *(const short8*)&Vth[(n * 16 + fr) * 72 + kk * 32 + 8 * fq];
      acc[n] = __builtin_amdgcn_mfma_f32_16x16x32_bf16(aa, bv, acc[n], 0, 0, 0);
    }
  }
  const size_t spb = (((size_t)(b * 16 + h) * 32) + c) * 8192;
#pragma unroll
  for (int n = 0; n < 8; ++n)
#pragma unroll
    for (int kk = 0; kk < 2; ++kk) {
      size_t soff = spb + (size_t)(n * 16 + fr) * 64 + kk * 32 + 8 * fq;
      short8 bh_ = *(const short8*)(Sph + soff);
      short8 bl_ = *(const short8*)(Spl + soff);
      acc[n] = __builtin_amdgcn_mfma_f32_16x16x32_bf16(aqh[kk], bh_, acc[n], 0, 0, 0);
      acc[n] = __builtin_amdgcn_mfma_f32_16x16x32_bf16(aqh[kk], bl_, acc[n], 0, 0, 0);
      acc[n] = __builtin_amdgcn_mfma_f32_16x16x32_bf16(aql[kk], bh_, acc[n], 0, 0, 0);
    }
#pragma unroll
  for (int n = 0; n < 8; ++n)
#pragma unroll
    for (int rr = 0; rr < 4; ++rr) {
      int tt = w * 16 + 4 * fq + rr;
      int vd = n * 16 + fr;
      u16 hh, ll;
      split2(acc[n][rr], hh, ll);
      size_t off = (rb + tt) * 2048 + h * 128 + vd;
      oh[off] = hh; ol[off] = ll;
    }
}

// ===========================================================================
extern "C" void kernel_launch(void* const* d_in, const int* in_sizes, int n_in,
                              void* d_out, int out_size, void* d_ws, size_t ws_size,
                              hipStream_t stream) {
  (void)in_sizes; (void)n_in; (void)out_size; (void)ws_size;
  const float* x  = (const float*)d_in[0];
  const float* Wq = (const float*)d_in[1];
  const float* Wk = (const float*)d_in[2];
  const float* Wv = (const float*)d_in[3];
  const float* gq = (const float*)d_in[4];
  const float* gk = (const float*)d_in[5];
  const float* gv = (const float*)d_in[6];
  const float* cq = (const float*)d_in[7];
  const float* ck = (const float*)d_in[8];
  const float* cv = (const float*)d_in[9];
  const float* Wa = (const float*)d_in[10];
  const float* Wb = (const float*)d_in[11];
  const float* Wo = (const float*)d_in[12];
  const float* Wg = (const float*)d_in[13];
  float* out = (float*)d_out;
  char* ws = (char*)d_ws;

  const size_t MiB = 1024 * 1024;
  // ---- workspace (peak exactly 256 MiB, liveness-audited; same as r14) ----
  u16* Wqkv_h = (u16*)(ws + 0 * MiB);      // 8  ([4096][1024])
  u16* Wqkv_l = (u16*)(ws + 8 * MiB);      // 8
  u16* Wo_h   = (u16*)(ws + 16 * MiB);     // 4
  u16* Wo_l   = (u16*)(ws + 20 * MiB);     // 4
  u16* Wg_h   = (u16*)(ws + 24 * MiB);     // 2
  u16* Wg_l   = (u16*)(ws + 26 * MiB);     // 2
  float* gbuf = (float*)(ws + 28 * MiB);   // 0.5
  u16* x_h    = (u16*)(ws + 32 * MiB);     // 16  [dead after qkv gemm]
  u16* x_l    = (u16*)(ws + 48 * MiB);     // 16
  float* qkv  = (float*)(ws + 64 * MiB);   // 128 [dead after convs]
  u16* q_h = (u16*)(ws + 192 * MiB);       // 16
  u16* q_l = (u16*)(ws + 208 * MiB);       // 16
  u16* k_h = (u16*)(ws + 224 * MiB);       // 16
  u16* k_l = (u16*)(ws + 240 * MiB);       // 16 (ends at 256)
  u16* vg_h = (u16*)(ws + 32 * MiB);       // 32 (x pair dead)
  u16* vg_l = (u16*)d_out;                 // 32 (d_out scratch; dead after scan)
  u16* Sp_h = (u16*)(ws + 96 * MiB);       // 32 (qkv dead)
  u16* Sp_l = (u16*)(ws + 128 * MiB);      // 32
  u16* o_h  = (u16*)(ws + 64 * MiB);       // 32 (qkv head dead)
  u16* o_l  = (u16*)d_out;                 // 32 (vg_l dead after scan)
  u16* p_h  = (u16*)(ws + 96 * MiB);       // 16 (Sp_h dead after pass2)
  u16* p_l  = (u16*)(ws + 112 * MiB);      // 16 (Sp_h tail)

  // prep: x cast/split + gab + all weight transcasts in one launch
  prep_all<<<dim3(15360), dim3(256), 0, stream>>>(x, x_h, x_l, Wa, Wb, gbuf,
                                                  Wq, Wk, Wv, Wo, Wg,
                                                  Wqkv_h, Wqkv_l, Wo_h, Wo_l, Wg_h, Wg_l);
  // merged QKV projection: 256^2-tile 4-phase pipelined split GEMM (r12)
  gemm_sp_big<<<dim3(16, 32), dim3(512), 0, stream>>>(x_h, x_l, Wqkv_h, Wqkv_l, qkv, 8192, 4096, 1024);
  // merged zrms+conv+silu for q,k,v -> split pairs (v pre-scaled by gab)
  conv_all<<<dim3(8192), dim3(1024), 0, stream>>>(qkv, cq, ck, cv, gq, gk, gv, gbuf,
                                                  q_h, q_l, k_h, k_l, vg_h, vg_l);
  // chunked recurrence
  scan_kernel<<<dim3(512), dim3(256), 0, stream>>>(k_h, k_l, vg_h, vg_l, Sp_h, Sp_l);
  pass2_sp<<<dim3(2048), dim3(256), 0, stream>>>(q_h, q_l, k_h, vg_h, Sp_h, Sp_l, o_h, o_l);
  // output projection (mid 2-phase, split pair out) + gated final GEMM
  gemm_sp_mid<1><<<dim3(4, 64), dim3(512), 0, stream>>>(o_h, o_l, Wo_h, Wo_l, nullptr, p_h, p_l, nullptr, nullptr, 8192, 1024, 2048);
  gemm_sp_mid<3><<<dim3(4, 64), dim3(512), 0, stream>>>(p_h, p_l, Wg_h, Wg_l, out, nullptr, nullptr, p_h, p_l, 8192, 1024, 1024);
}

// Round 18
// 653.309 us; speedup vs baseline: 1.0290x; 1.0290x over previous
//
#include <hip/hip_runtime.h>
#include <hip/hip_bf16.h>
#include <math.h>

#define RTOT 8192      // B*T
#define TSEQ 2048

typedef __attribute__((ext_vector_type(8))) short short8;
typedef __attribute__((ext_vector_type(4))) float f32x4;
typedef unsigned short u16;
typedef unsigned int u32;

union U16x8 { uint4 v; u16 s[8]; };

__device__ __forceinline__ float sigmoidf_(float x) { return 1.f / (1.f + expf(-x)); }
__device__ __forceinline__ float bf2f(u16 v) { u32 u = ((u32)v) << 16; float f; __builtin_memcpy(&f, &u, 4); return f; }
__device__ __forceinline__ u16 f2bf(float f) {
  u32 u; __builtin_memcpy(&u, &f, 4);
  u32 r = (u + 0x7FFFu + ((u >> 16) & 1u)) >> 16;
  return (u16)r;
}
// split f32 -> hi bf16 + lo bf16 (residual)
__device__ __forceinline__ void split2(float x, u16& h, u16& l) {
  u16 hh = f2bf(x);
  float hf = bf2f(hh);
  h = hh; l = f2bf(x - hf);
}

typedef const void __attribute__((address_space(1))) gvoid_t;
typedef void __attribute__((address_space(3))) lvoid_t;
__device__ __forceinline__ void gload_lds16(const void* g, void* l) {
  __builtin_amdgcn_global_load_lds((gvoid_t*)g, (lvoid_t*)l, 16, 0, 0);
}

// XCD-chunked bijective block remap (nwg % 8 == 0 required)
__device__ __forceinline__ void xcd_remap(int& bx, int& by) {
  int gx = gridDim.x, nwg = gx * gridDim.y;
  int bid = blockIdx.y * gx + blockIdx.x;
  int cpx = nwg >> 3;
  int swz = (bid & 7) * cpx + (bid >> 3);
  bx = swz % gx; by = swz / gx;
}

// ======= 256^2-tile 4-phase pipelined split-bf16 GEMM (QKV) — r12 proven ====
__global__ __launch_bounds__(512) void gemm_sp_big(const u16* __restrict__ Ah, const u16* __restrict__ Al,
                                                   const u16* __restrict__ Bh, const u16* __restrict__ Bl,
                                                   float* __restrict__ Cf,
                                                   int M, int N, int K) {
  __shared__ u16 lds[2][4][256 * 32];   // [buf][Ah,Al,Bh,Bl][row][k]
  int bx, by; xcd_remap(bx, by);
  const int tid = threadIdx.x;
  const int l = tid & 63, w = tid >> 6;
  const int wr = w >> 2, wc = w & 3;           // 2 x 4 wave grid
  const int m0 = by * 256, n0 = bx * 256;
  const int fr = l & 15, fq = l >> 4;
  const int koff = 8 * (fq ^ (fr & 3));        // swizzled read granule
  const int srow = tid >> 2;
  const int scol = ((tid & 3) ^ (srow & 3)) * 8;
  const u16* gA_h = Ah + (size_t)(m0 + srow) * K + scol;
  const u16* gA_l = Al + (size_t)(m0 + srow) * K + scol;
  const u16* gB_h = Bh + (size_t)(n0 + srow) * K + scol;
  const u16* gB_l = Bl + (size_t)(n0 + srow) * K + scol;
  const int lo = srow * 32 + (tid & 3) * 8;    // linear LDS dest
  const int NT = K >> 5;

#define STG(buf, mat, src, t)                                 \
  do {                                                        \
    const int k0_ = (t) << 5;                                 \
    gload_lds16(src + k0_, &lds[buf][mat][lo]);               \
    gload_lds16(src + 128 * K + k0_, &lds[buf][mat][lo + 4096]); \
  } while (0)

#define MFMA_PAIR(mi, a_h, a_l)                                                        \
  do {                                                                                 \
    _Pragma("unroll")                                                                  \
    for (int n = 0; n < 4; ++n) {                                                      \
      acc[mi][n] = __builtin_amdgcn_mfma_f32_16x16x32_bf16(a_h, bh8[n], acc[mi][n], 0, 0, 0); \
      acc[mi][n] = __builtin_amdgcn_mfma_f32_16x16x32_bf16(a_h, bl8[n], acc[mi][n], 0, 0, 0); \
      acc[mi][n] = __builtin_amdgcn_mfma_f32_16x16x32_bf16(a_l, bh8[n], acc[mi][n], 0, 0, 0); \
    }                                                                                  \
  } while (0)

  f32x4 acc[8][4] = {};
  STG(0, 0, gA_h, 0); STG(0, 1, gA_l, 0); STG(0, 2, gB_h, 0); STG(0, 3, gB_l, 0);
  asm volatile("s_waitcnt vmcnt(0)" ::: "memory");
  __builtin_amdgcn_s_barrier();

  for (int t = 0; t < NT; ++t) {
    const int c = t & 1, o = c ^ 1;
    const bool pf = (t + 1 < NT);
    short8 bh8[4], bl8[4];
    // P0: B-frags + A m=0,1 | stage B(t+1)
    {
#pragma unroll
      for (int n = 0; n < 4; ++n) {
        bh8[n] = *(const short8*)&lds[c][2][(wc * 64 + n * 16 + fr) * 32 + koff];
        bl8[n] = *(const short8*)&lds[c][3][(wc * 64 + n * 16 + fr) * 32 + koff];
      }
      short8 a0h = *(const short8*)&lds[c][0][(wr * 128 + 0 * 16 + fr) * 32 + koff];
      short8 a1h = *(const short8*)&lds[c][0][(wr * 128 + 1 * 16 + fr) * 32 + koff];
      short8 a0l = *(const short8*)&lds[c][1][(wr * 128 + 0 * 16 + fr) * 32 + koff];
      short8 a1l = *(const short8*)&lds[c][1][(wr * 128 + 1 * 16 + fr) * 32 + koff];
      if (pf) { STG(o, 2, gB_h, t + 1); STG(o, 3, gB_l, t + 1); }
      __builtin_amdgcn_s_barrier();
      asm volatile("s_waitcnt lgkmcnt(0)" ::: "memory");
      __builtin_amdgcn_s_setprio(1);
      MFMA_PAIR(0, a0h, a0l);
      MFMA_PAIR(1, a1h, a1l);
      __builtin_amdgcn_s_setprio(0);
      __builtin_amdgcn_s_barrier();
    }
    // P1: A m=2,3 | stage A(t+1)
    {
      short8 a0h = *(const short8*)&lds[c][0][(wr * 128 + 2 * 16 + fr) * 32 + koff];
      short8 a1h = *(const short8*)&lds[c][0][(wr * 128 + 3 * 16 + fr) * 32 + koff];
      short8 a0l = *(const short8*)&lds[c][1][(wr * 128 + 2 * 16 + fr) * 32 + koff];
      short8 a1l = *(const short8*)&lds[c][1][(wr * 128 + 3 * 16 + fr) * 32 + koff];
      if (pf) { STG(o, 0, gA_h, t + 1); STG(o, 1, gA_l, t + 1); }
      __builtin_amdgcn_s_barrier();
      asm volatile("s_waitcnt lgkmcnt(0)" ::: "memory");
      __builtin_amdgcn_s_setprio(1);
      MFMA_PAIR(2, a0h, a0l);
      MFMA_PAIR(3, a1h, a1l);
      __builtin_amdgcn_s_setprio(0);
      __builtin_amdgcn_s_barrier();
    }
    // P2: A m=4,5
    {
      short8 a0h = *(const short8*)&lds[c][0][(wr * 128 + 4 * 16 + fr) * 32 + koff];
      short8 a1h = *(const short8*)&lds[c][0][(wr * 128 + 5 * 16 + fr) * 32 + koff];
      short8 a0l = *(const short8*)&lds[c][1][(wr * 128 + 4 * 16 + fr) * 32 + koff];
      short8 a1l = *(const short8*)&lds[c][1][(wr * 128 + 5 * 16 + fr) * 32 + koff];
      __builtin_amdgcn_s_barrier();
      asm volatile("s_waitcnt lgkmcnt(0)" ::: "memory");
      __builtin_amdgcn_s_setprio(1);
      MFMA_PAIR(4, a0h, a0l);
      MFMA_PAIR(5, a1h, a1l);
      __builtin_amdgcn_s_setprio(0);
      __builtin_amdgcn_s_barrier();
    }
    // P3: A m=6,7 | drain t+1 loads
    {
      short8 a0h = *(const short8*)&lds[c][0][(wr * 128 + 6 * 16 + fr) * 32 + koff];
      short8 a1h = *(const short8*)&lds[c][0][(wr * 128 + 7 * 16 + fr) * 32 + koff];
      short8 a0l = *(const short8*)&lds[c][1][(wr * 128 + 6 * 16 + fr) * 32 + koff];
      short8 a1l = *(const short8*)&lds[c][1][(wr * 128 + 7 * 16 + fr) * 32 + koff];
      __builtin_amdgcn_s_barrier();
      asm volatile("s_waitcnt lgkmcnt(0)" ::: "memory");
      __builtin_amdgcn_s_setprio(1);
      MFMA_PAIR(6, a0h, a0l);
      MFMA_PAIR(7, a1h, a1l);
      __builtin_amdgcn_s_setprio(0);
      if (pf) asm volatile("s_waitcnt vmcnt(0)" ::: "memory");
      __builtin_amdgcn_s_barrier();
    }
  }
#undef STG
#undef MFMA_PAIR
#pragma unroll
  for (int m = 0; m < 8; ++m)
#pragma unroll
    for (int n = 0; n < 4; ++n)
#pragma unroll
      for (int r = 0; r < 4; ++r)
        Cf[(size_t)(m0 + wr * 128 + m * 16 + 4 * fq + r) * N + (n0 + wc * 64 + n * 16 + fr)] = acc[m][n][r];
}

// ======= BM=128/BN=256 2-phase pipelined split-bf16 GEMM (Wo/Wg) ===========
// EPI 1: split pair out.  EPI 3: Cf = (Pinh+Pinl) * sigmoid(acc)
template<int EPI>
__global__ __launch_bounds__(512) void gemm_sp_mid(const u16* __restrict__ Ah, const u16* __restrict__ Al,
                                                   const u16* __restrict__ Bh, const u16* __restrict__ Bl,
                                                   float* __restrict__ Cf, u16* __restrict__ Ph,
                                                   u16* __restrict__ Pl, const u16* __restrict__ Pinh,
                                                   const u16* __restrict__ Pinl,
                                                   int M, int N, int K) {
  __shared__ u16 lds[2][24576];
  int bx, by; xcd_remap(bx, by);
  const int tid = threadIdx.x;
  const int l = tid & 63, w = tid >> 6;
  const int wr = w >> 2, wc = w & 3;           // 2M x 4N
  const int m0 = by * 128, n0 = bx * 256;
  const int fr = l & 15, fq = l >> 4;
  const int koff = 8 * (fq ^ (fr & 3));
  const int srow = tid >> 2;                   // 0..127
  const int scol = ((tid & 3) ^ (srow & 3)) * 8;
  const u16* gA_h = Ah + (size_t)(m0 + srow) * K + scol;
  const u16* gA_l = Al + (size_t)(m0 + srow) * K + scol;
  const u16* gB_h = Bh + (size_t)(n0 + srow) * K + scol;
  const u16* gB_l = Bl + (size_t)(n0 + srow) * K + scol;
  const int lo = srow * 32 + (tid & 3) * 8;
  const int NT = K >> 5;

#define STGA(buf, t)                                              \
  do {                                                            \
    const int k0_ = (t) << 5;                                     \
    gload_lds16(gA_h + k0_, &lds[buf][lo]);                       \
    gload_lds16(gA_l + k0_, &lds[buf][4096 + lo]);                \
  } while (0)
#define STGB(buf, t)                                              \
  do {                                                            \
    const int k0_ = (t) << 5;                                     \
    gload_lds16(gB_h + k0_, &lds[buf][8192 + lo]);                \
    gload_lds16(gB_h + 128 * K + k0_, &lds[buf][8192 + 4096 + lo]); \
    gload_lds16(gB_l + k0_, &lds[buf][16384 + lo]);               \
    gload_lds16(gB_l + 128 * K + k0_, &lds[buf][16384 + 4096 + lo]); \
  } while (0)
#define MFMA_PAIR(mi, a_h, a_l)                                                        \
  do {                                                                                 \
    _Pragma("unroll")                                                                  \
    for (int n = 0; n < 4; ++n) {                                                      \
      acc[mi][n] = __builtin_amdgcn_mfma_f32_16x16x32_bf16(a_h, bh8[n], acc[mi][n], 0, 0, 0); \
      acc[mi][n] = __builtin_amdgcn_mfma_f32_16x16x32_bf16(a_h, bl8[n], acc[mi][n], 0, 0, 0); \
      acc[mi][n] = __builtin_amdgcn_mfma_f32_16x16x32_bf16(a_l, bh8[n], acc[mi][n], 0, 0, 0); \
    }                                                                                  \
  } while (0)

  f32x4 acc[4][4] = {};
  STGA(0, 0); STGB(0, 0);
  asm volatile("s_waitcnt vmcnt(0)" ::: "memory");
  __builtin_amdgcn_s_barrier();

  for (int t = 0; t < NT; ++t) {
    const int c = t & 1, o = c ^ 1;
    const bool pf = (t + 1 < NT);
    short8 bh8[4], bl8[4];
    // P0: B-frags + A m=0,1 | stage B(t+1)
    {
#pragma unroll
      for (int n = 0; n < 4; ++n) {
        bh8[n] = *(const short8*)&lds[c][8192 + (wc * 64 + n * 16 + fr) * 32 + koff];
        bl8[n] = *(const short8*)&lds[c][16384 + (wc * 64 + n * 16 + fr) * 32 + koff];
      }
      short8 a0h = *(const short8*)&lds[c][(wr * 64 + 0 * 16 + fr) * 32 + koff];
      short8 a1h = *(const short8*)&lds[c][(wr * 64 + 1 * 16 + fr) * 32 + koff];
      short8 a0l = *(const short8*)&lds[c][4096 + (wr * 64 + 0 * 16 + fr) * 32 + koff];
      short8 a1l = *(const short8*)&lds[c][4096 + (wr * 64 + 1 * 16 + fr) * 32 + koff];
      if (pf) STGB(o, t + 1);
      __builtin_amdgcn_s_barrier();
      asm volatile("s_waitcnt lgkmcnt(0)" ::: "memory");
      __builtin_amdgcn_s_setprio(1);
      MFMA_PAIR(0, a0h, a0l);
      MFMA_PAIR(1, a1h, a1l);
      __builtin_amdgcn_s_setprio(0);
      __builtin_amdgcn_s_barrier();
    }
    // P1: A m=2,3 | stage A(t+1) | drain
    {
      short8 a0h = *(const short8*)&lds[c][(wr * 64 + 2 * 16 + fr) * 32 + koff];
      short8 a1h = *(const short8*)&lds[c][(wr * 64 + 3 * 16 + fr) * 32 + koff];
      short8 a0l = *(const short8*)&lds[c][4096 + (wr * 64 + 2 * 16 + fr) * 32 + koff];
      short8 a1l = *(const short8*)&lds[c][4096 + (wr * 64 + 3 * 16 + fr) * 32 + koff];
      if (pf) STGA(o, t + 1);
      __builtin_amdgcn_s_barrier();
      asm volatile("s_waitcnt lgkmcnt(0)" ::: "memory");
      __builtin_amdgcn_s_setprio(1);
      MFMA_PAIR(2, a0h, a0l);
      MFMA_PAIR(3, a1h, a1l);
      __builtin_amdgcn_s_setprio(0);
      if (pf) asm volatile("s_waitcnt vmcnt(0)" ::: "memory");
      __builtin_amdgcn_s_barrier();
    }
  }
#undef STGA
#undef STGB
#undef MFMA_PAIR
  const int rbase = m0 + wr * 64 + 4 * fq;
  const int cbase = n0 + wc * 64 + fr;
#pragma unroll
  for (int m = 0; m < 4; ++m)
#pragma unroll
    for (int n = 0; n < 4; ++n)
#pragma unroll
      for (int r = 0; r < 4; ++r) {
        size_t idx = (size_t)(rbase + m * 16 + r) * N + (cbase + n * 16);
        float v = acc[m][n][r];
        if (EPI == 1) {
          u16 h, lo2; split2(v, h, lo2);
          Ph[idx] = h; Pl[idx] = lo2;
        } else {
          float pin = bf2f(Pinh[idx]) + bf2f(Pinl[idx]);
          Cf[idx] = pin * sigmoidf_(v);
        }
      }
}

// ======= merged weight cast+transpose+split (all 5 weights, 1 launch) =======
__global__ __launch_bounds__(256) void transcast_all(const float* __restrict__ Wq,
                                                     const float* __restrict__ Wk,
                                                     const float* __restrict__ Wv,
                                                     const float* __restrict__ Wo,
                                                     const float* __restrict__ Wg,
                                                     u16* __restrict__ Wqkv_h, u16* __restrict__ Wqkv_l,
                                                     u16* __restrict__ Wo_h, u16* __restrict__ Wo_l,
                                                     u16* __restrict__ Wg_h, u16* __restrict__ Wg_l) {
  __shared__ float t[32][33];
  const int bid = blockIdx.x;
  const float* W; u16 *Th, *Tl; int K, N, lb;
  if (bid < 1024)      { W = Wq; Th = Wqkv_h;              Tl = Wqkv_l;              K = 1024; N = 1024; lb = bid; }
  else if (bid < 2048) { W = Wk; Th = Wqkv_h + 1024*1024;  Tl = Wqkv_l + 1024*1024;  K = 1024; N = 1024; lb = bid - 1024; }
  else if (bid < 4096) { W = Wv; Th = Wqkv_h + 2048*1024;  Tl = Wqkv_l + 2048*1024;  K = 1024; N = 2048; lb = bid - 2048; }
  else if (bid < 6144) { W = Wo; Th = Wo_h;                Tl = Wo_l;                K = 2048; N = 1024; lb = bid - 4096; }
  else                 { W = Wg; Th = Wg_h;                Tl = Wg_l;                K = 1024; N = 1024; lb = bid - 6144; }
  const int nx = N >> 5;
  const int n0 = (lb % nx) * 32, k0 = (lb / nx) * 32;
  const int c = threadIdx.x & 31, rq = threadIdx.x >> 5;
#pragma unroll
  for (int i = 0; i < 4; ++i) t[rq * 4 + i][c] = W[(size_t)(k0 + rq * 4 + i) * N + n0 + c];
  __syncthreads();
#pragma unroll
  for (int i = 0; i < 4; ++i) {
    float v = t[c][rq * 4 + i];
    u16 h, lo; split2(v, h, lo);
    size_t idx = (size_t)(n0 + rq * 4 + i) * K + k0 + c;
    Th[idx] = h; Tl[idx] = lo;
  }
}

// ======= fused x cast+split AND gab = sigmoid(x@Wa)*sigmoid(x@Wb) ==========
__global__ __launch_bounds__(256) void castx_gab(const float* __restrict__ x,
                                                 u16* __restrict__ xh, u16* __restrict__ xl,
                                                 const float* __restrict__ Wa,
                                                 const float* __restrict__ Wb,
                                                 float* __restrict__ gout) {
  __shared__ float xs[1024];
  __shared__ float partial[256];
  const int tid = threadIdx.x;
  const size_t row = blockIdx.x;
  float4 v = *(const float4*)(x + row * 1024 + tid * 4);
  *(float4*)(&xs[tid * 4]) = v;
  ushort4 hh, ll;
  split2(v.x, hh.x, ll.x); split2(v.y, hh.y, ll.y);
  split2(v.z, hh.z, ll.z); split2(v.w, hh.w, ll.w);
  *(ushort4*)(xh + row * 1024 + tid * 4) = hh;
  *(ushort4*)(xl + row * 1024 + tid * 4) = ll;
  __syncthreads();
  const int h = tid & 31;
  const int seg = tid >> 5;
  const float* W = (h < 16) ? Wa : Wb;
  const int col = h & 15;
  float s = 0.f;
  const int k0 = seg * 128;
  for (int k = 0; k < 128; ++k) s = fmaf(xs[k0 + k], W[(size_t)(k0 + k) * 16 + col], s);
  partial[tid] = s;
  __syncthreads();
  if (tid < 32) {
    float t2 = 0.f;
#pragma unroll
    for (int j = 0; j < 8; ++j) t2 += partial[j * 32 + tid];
    partial[tid] = t2;
  }
  __syncthreads();
  if (tid < 16)
    gout[row * 16 + tid] = sigmoidf_(partial[tid]) * sigmoidf_(partial[tid + 16]);
}

// ======= fused zrms+conv+SiLU for q AND k in one launch (C=1024) ============
__global__ __launch_bounds__(256) void conv_qk(const float* __restrict__ qkv,
                                               const float* __restrict__ cq,
                                               const float* __restrict__ ck,
                                               const float* __restrict__ gq,
                                               const float* __restrict__ gk,
                                               u16* __restrict__ q_h, u16* __restrict__ q_l,
                                               u16* __restrict__ k_h, u16* __restrict__ k_l) {
  constexpr int C = 1024;
  constexpr int NW = 4;
  __shared__ float redA[NW * 4];
  __shared__ float redB[NW * 4];
  const int tid = threadIdx.x;
  const int bid = blockIdx.x;
  const bool isq = bid < 8192;
  const int lb = isq ? bid : bid - 8192;
  const float* zn = isq ? qkv : qkv + 1024;
  const float* w  = isq ? cq : ck;
  const float* g  = isq ? gq : gk;
  u16* oh = isq ? q_h : k_h;
  u16* ol = isq ? q_l : k_l;
  const int row = ((lb & 7) << 10) + (lb >> 3);   // XCD-chunked within half
  const int t = row & (TSEQ - 1);
  const int c = tid * 4;
  const int lane = tid & 63, wid = tid >> 6;
  float4 xv[4];
  float psum[4];
#pragma unroll
  for (int d = 0; d < 4; ++d) {
    if (t - d >= 0) xv[d] = *(const float4*)(zn + (size_t)(row - d) * 4096 + c);
    else { xv[d].x = 0.f; xv[d].y = 0.f; xv[d].z = 0.f; xv[d].w = 0.f; }
    psum[d] = xv[d].x + xv[d].y + xv[d].z + xv[d].w;
  }
#pragma unroll
  for (int d = 0; d < 4; ++d)
#pragma unroll
    for (int o = 32; o > 0; o >>= 1) psum[d] += __shfl_xor(psum[d], o, 64);
  if (lane == 0) {
    redA[wid * 4 + 0] = psum[0]; redA[wid * 4 + 1] = psum[1];
    redA[wid * 4 + 2] = psum[2]; redA[wid * 4 + 3] = psum[3];
  }
  __syncthreads();
  float mean[4];
#pragma unroll
  for (int d = 0; d < 4; ++d) {
    float s = 0.f;
#pragma unroll
    for (int j = 0; j < NW; ++j) s += redA[j * 4 + d];
    mean[d] = s * (1.f / C);
  }
  float psq[4];
#pragma unroll
  for (int d = 0; d < 4; ++d) {
    float a = xv[d].x - mean[d], b = xv[d].y - mean[d];
    float e = xv[d].z - mean[d], f = xv[d].w - mean[d];
    psq[d] = a * a + b * b + e * e + f * f;
  }
#pragma unroll
  for (int d = 0; d < 4; ++d)
#pragma unroll
    for (int o = 32; o > 0; o >>= 1) psq[d] += __shfl_xor(psq[d], o, 64);
  if (lane == 0) {
    redB[wid * 4 + 0] = psq[0]; redB[wid * 4 + 1] = psq[1];
    redB[wid * 4 + 2] = psq[2]; redB[wid * 4 + 3] = psq[3];
  }
  __syncthreads();
  float rstd[4];
#pragma unroll
  for (int d = 0; d < 4; ++d) {
    float s = 0.f;
#pragma unroll
    for (int j = 0; j < NW; ++j) s += redB[j * 4 + d];
    rstd[d] = rsqrtf(s * (1.f / C) + 1e-5f);
  }
  float4 g4 = *(const float4*)(g + c);
  float4 acc; acc.x = 0.f; acc.y = 0.f; acc.z = 0.f; acc.w = 0.f;
#pragma unroll
  for (int d = 0; d < 4; ++d) {
    if (t - d >= 0) {
      float4 wv = *(const float4*)(w + (size_t)(3 - d) * C + c);
      acc.x = fmaf((xv[d].x - mean[d]) * rstd[d] * g4.x, wv.x, acc.x);
      acc.y = fmaf((xv[d].y - mean[d]) * rstd[d] * g4.y, wv.y, acc.y);
      acc.z = fmaf((xv[d].z - mean[d]) * rstd[d] * g4.z, wv.z, acc.z);
      acc.w = fmaf((xv[d].w - mean[d]) * rstd[d] * g4.w, wv.w, acc.w);
    }
  }
  float a0 = acc.x * sigmoidf_(acc.x);
  float a1 = acc.y * sigmoidf_(acc.y);
  float a2 = acc.z * sigmoidf_(acc.z);
  float a3 = acc.w * sigmoidf_(acc.w);
  ushort4 hh, ll;
  split2(a0, hh.x, ll.x); split2(a1, hh.y, ll.y);
  split2(a2, hh.z, ll.z); split2(a3, hh.w, ll.w);
  *(ushort4*)(oh + (size_t)row * C + c) = hh;
  *(ushort4*)(ol + (size_t)row * C + c) = ll;
}

// ======= fused zrms+conv+SiLU for v (C=2048, g-scaled) ======================
template<int C, int GSCALE>
__global__ __launch_bounds__(C / 4) void conv_fs(const float* __restrict__ zn,
                                                 const float* __restrict__ w,
                                                 const float* __restrict__ g,
                                                 const float* __restrict__ gab,
                                                 u16* __restrict__ oh,
                                                 u16* __restrict__ ol) {
  constexpr int NW = C / 256;
  __shared__ float redA[NW * 4];
  __shared__ float redB[NW * 4];
  const int tid = threadIdx.x;
  const int bid = blockIdx.x;
  const int row = ((bid & 7) << 10) + (bid >> 3);   // XCD-chunked (8192 blocks)
  const int t = row & (TSEQ - 1);
  const int c = tid * 4;
  const int lane = tid & 63, wid = tid >> 6;
  float4 xv[4];
  float psum[4];
#pragma unroll
  for (int d = 0; d < 4; ++d) {
    if (t - d >= 0) xv[d] = *(const float4*)(zn + (size_t)(row - d) * 4096 + c);
    else { xv[d].x = 0.f; xv[d].y = 0.f; xv[d].z = 0.f; xv[d].w = 0.f; }
    psum[d] = xv[d].x + xv[d].y + xv[d].z + xv[d].w;
  }
#pragma unroll
  for (int d = 0; d < 4; ++d)
#pragma unroll
    for (int o = 32; o > 0; o >>= 1) psum[d] += __shfl_xor(psum[d], o, 64);
  if (lane == 0) {
    redA[wid * 4 + 0] = psum[0]; redA[wid * 4 + 1] = psum[1];
    redA[wid * 4 + 2] = psum[2]; redA[wid * 4 + 3] = psum[3];
  }
  __syncthreads();
  float mean[4];
#pragma unroll
  for (int d = 0; d < 4; ++d) {
    float s = 0.f;
#pragma unroll
    for (int j = 0; j < NW; ++j) s += redA[j * 4 + d];
    mean[d] = s * (1.f / C);
  }
  float psq[4];
#pragma unroll
  for (int d = 0; d < 4; ++d) {
    float a = xv[d].x - mean[d], b = xv[d].y - mean[d];
    float e = xv[d].z - mean[d], f = xv[d].w - mean[d];
    psq[d] = a * a + b * b + e * e + f * f;
  }
#pragma unroll
  for (int d = 0; d < 4; ++d)
#pragma unroll
    for (int o = 32; o > 0; o >>= 1) psq[d] += __shfl_xor(psq[d], o, 64);
  if (lane == 0) {
    redB[wid * 4 + 0] = psq[0]; redB[wid * 4 + 1] = psq[1];
    redB[wid * 4 + 2] = psq[2]; redB[wid * 4 + 3] = psq[3];
  }
  __syncthreads();
  float rstd[4];
#pragma unroll
  for (int d = 0; d < 4; ++d) {
    float s = 0.f;
#pragma unroll
    for (int j = 0; j < NW; ++j) s += redB[j * 4 + d];
    rstd[d] = rsqrtf(s * (1.f / C) + 1e-5f);
  }
  float4 g4 = *(const float4*)(g + c);
  float4 acc; acc.x = 0.f; acc.y = 0.f; acc.z = 0.f; acc.w = 0.f;
#pragma unroll
  for (int d = 0; d < 4; ++d) {
    if (t - d >= 0) {
      float4 wv = *(const float4*)(w + (size_t)(3 - d) * C + c);
      acc.x = fmaf((xv[d].x - mean[d]) * rstd[d] * g4.x, wv.x, acc.x);
      acc.y = fmaf((xv[d].y - mean[d]) * rstd[d] * g4.y, wv.y, acc.y);
      acc.z = fmaf((xv[d].z - mean[d]) * rstd[d] * g4.z, wv.z, acc.z);
      acc.w = fmaf((xv[d].w - mean[d]) * rstd[d] * g4.w, wv.w, acc.w);
    }
  }
  float a0 = acc.x * sigmoidf_(acc.x);
  float a1 = acc.y * sigmoidf_(acc.y);
  float a2 = acc.z * sigmoidf_(acc.z);
  float a3 = acc.w * sigmoidf_(acc.w);
  if (GSCALE) {
    float gv = gab[(size_t)row * 16 + (c >> 7)];
    a0 *= gv; a1 *= gv; a2 *= gv; a3 *= gv;
  }
  ushort4 hh, ll;
  split2(a0, hh.x, ll.x); split2(a1, hh.y, ll.y);
  split2(a2, hh.z, ll.z); split2(a3, hh.w, ll.w);
  *(ushort4*)(oh + (size_t)row * C + c) = hh;
  *(ushort4*)(ol + (size_t)row * C + c) = ll;
}

// ======= scan: exclusive chunk-prefix of Vg^T K, kd-split (512 blocks) ======
__global__ __launch_bounds__(256) void scan_kernel(const u16* __restrict__ kh,
                                                   const u16* __restrict__ kl,
                                                   const u16* __restrict__ vgh,
                                                   const u16* __restrict__ vgl,
                                                   u16* __restrict__ Sph,
                                                   u16* __restrict__ Spl) {
  __shared__ float Ks[64][36];
  __shared__ float Vs[64][36];
  const int tid = threadIdx.x;
  const int bid = blockIdx.x;
  const int kq = bid & 1, vq = (bid >> 1) & 3, h = (bid >> 3) & 15, b = bid >> 7;
  const size_t rb = (size_t)b * TSEQ;
  const int vd_t = tid >> 3, kd0 = (tid & 7) * 4;
  float S[4] = {};
  const int sr = tid >> 2;
  const int cc0 = (tid & 3) * 8;
  for (int c = 0; c < 32; ++c) {
    {
      size_t koffg = (rb + (size_t)c * 64 + sr) * 1024 + h * 64 + kq * 32 + cc0;
      U16x8 a0, b0;
      a0.v = *(const uint4*)(kh + koffg);
      b0.v = *(const uint4*)(kl + koffg);
#pragma unroll
      for (int j = 0; j < 8; ++j) Ks[sr][cc0 + j] = bf2f(a0.s[j]) + bf2f(b0.s[j]);
      size_t voffg = (rb + (size_t)c * 64 + sr) * 2048 + h * 128 + vq * 32 + cc0;
      U16x8 va, vb;
      va.v = *(const uint4*)(vgh + voffg);
      vb.v = *(const uint4*)(vgl + voffg);
#pragma unroll
      for (int j = 0; j < 8; ++j) Vs[sr][cc0 + j] = bf2f(va.s[j]) + bf2f(vb.s[j]);
    }
    {
      size_t spc = (((size_t)(b * 16 + h) * 32) + c) * 8192
                 + (size_t)(vq * 32 + vd_t) * 64 + kq * 32 + kd0;
      ushort4 h0, l0;
      split2(S[0], h0.x, l0.x); split2(S[1], h0.y, l0.y);
      split2(S[2], h0.z, l0.z); split2(S[3], h0.w, l0.w);
      *(ushort4*)(Sph + spc) = h0;
      *(ushort4*)(Spl + spc) = l0;
    }
    __syncthreads();
    for (int s = 0; s < 64; ++s) {
      float vv = Vs[s][vd_t];
      float kv[4];
      *(float4*)kv = *(const float4*)&Ks[s][kd0];
#pragma unroll
      for (int j = 0; j < 4; ++j) S[j] = fmaf(vv, kv[j], S[j]);
    }
    __syncthreads();
  }
}

// ======= pass2: O = mask(QK^T) Vg + Q Sp^T  (MFMA, split; proven) ===========
__global__ __launch_bounds__(256) void pass2_sp(const u16* __restrict__ qh,
                                                const u16* __restrict__ ql,
                                                const u16* __restrict__ kh,
                                                const u16* __restrict__ vgh,
                                                const u16* __restrict__ Sph,
                                                const u16* __restrict__ Spl,
                                                u16* __restrict__ oh,
                                                u16* __restrict__ ol) {
  __shared__ u16 Qsh[64 * 72];
  __shared__ u16 Qsl[64 * 72];
  __shared__ u16 Ksm[64 * 72];
  __shared__ u16 Am[64 * 72];
  __shared__ u16 Vth[128 * 72];
  const int tid = threadIdx.x;
  const int l = tid & 63, w = tid >> 6;
  const int bid = blockIdx.x;
  const int c = bid & 31, h = (bid >> 5) & 15, b = bid >> 9;
  const size_t rb = (size_t)b * TSEQ + c * 64;
  const int fr = l & 15, fq = l >> 4;
  {
    int r = tid >> 2, c0 = (tid & 3) * 16;
    size_t off = (rb + r) * 1024 + h * 64 + c0;
    *(uint4*)&Qsh[r * 72 + c0]     = *(const uint4*)(qh + off);
    *(uint4*)&Qsh[r * 72 + c0 + 8] = *(const uint4*)(qh + off + 8);
    *(uint4*)&Qsl[r * 72 + c0]     = *(const uint4*)(ql + off);
    *(uint4*)&Qsl[r * 72 + c0 + 8] = *(const uint4*)(ql + off + 8);
    *(uint4*)&Ksm[r * 72 + c0]     = *(const uint4*)(kh + off);
    *(uint4*)&Ksm[r * 72 + c0 + 8] = *(const uint4*)(kh + off + 8);
  }
  {
    int s = tid >> 2, vd0 = (tid & 3) * 32;
    size_t off = (rb + s) * 2048 + h * 128 + vd0;
#pragma unroll
    for (int m4 = 0; m4 < 4; ++m4) {
      U16x8 r_; r_.v = *(const uint4*)(vgh + off + m4 * 8);
#pragma unroll
      for (int j = 0; j < 8; ++j) Vth[(vd0 + m4 * 8 + j) * 72 + s] = r_.s[j];
    }
  }
  __syncthreads();
  short8 aqh[2], aql[2];
#pragma unroll
  for (int kk = 0; kk < 2; ++kk) {
    aqh[kk] = *(const short8*)&Qsh[(w * 16 + fr) * 72 + kk * 32 + 8 * fq];
    aql[kk] = *(const short8*)&Qsl[(w * 16 + fr) * 72 + kk * 32 + 8 * fq];
  }
  f32x4 accA[4] = {};
#pragma unroll
  for (int n = 0; n < 4; ++n)
#pragma unroll
    for (int kk = 0; kk < 2; ++kk) {
      short8 bk = *(const short8*)&Ksm[(n * 16 + fr) * 72 + kk * 32 + 8 * fq];
      accA[n] = __builtin_amdgcn_mfma_f32_16x16x32_bf16(aqh[kk], bk, accA[n], 0, 0, 0);
    }
#pragma unroll
  for (int n = 0; n < 4; ++n)
#pragma unroll
    for (int rr = 0; rr < 4; ++rr) {
      int tt = w * 16 + 4 * fq + rr;
      int s = n * 16 + fr;
      Am[tt * 72 + s] = f2bf((s <= tt) ? accA[n][rr] : 0.f);
    }
  __syncthreads();
  f32x4 acc[8] = {};
#pragma unroll
  for (int kk = 0; kk < 2; ++kk) {
    short8 aa = *(const short8*)&Am[(w * 16 + fr) * 72 + kk * 32 + 8 * fq];
#pragma unroll
    for (int n = 0; n < 8; ++n) {
      short8 bv = *(const short8*)&Vth[(n * 16 + fr) * 72 + kk * 32 + 8 * fq];
      acc[n] = __builtin_amdgcn_mfma_f32_16x16x32_bf16(aa, bv, acc[n], 0, 0, 0);
    }
  }
  const size_t spb = (((size_t)(b * 16 + h) * 32) + c) * 8192;
#pragma unroll
  for (int n = 0; n < 8; ++n)
#pragma unroll
    for (int kk = 0; kk < 2; ++kk) {
      size_t soff = spb + (size_t)(n * 16 + fr) * 64 + kk * 32 + 8 * fq;
      short8 bh_ = *(const short8*)(Sph + soff);
      short8 bl_ = *(const short8*)(Spl + soff);
      acc[n] = __builtin_amdgcn_mfma_f32_16x16x32_bf16(aqh[kk], bh_, acc[n], 0, 0, 0);
      acc[n] = __builtin_amdgcn_mfma_f32_16x16x32_bf16(aqh[kk], bl_, acc[n], 0, 0, 0);
      acc[n] = __builtin_amdgcn_mfma_f32_16x16x32_bf16(aql[kk], bh_, acc[n], 0, 0, 0);
    }
#pragma unroll
  for (int n = 0; n < 8; ++n)
#pragma unroll
    for (int rr = 0; rr < 4; ++rr) {
      int tt = w * 16 + 4 * fq + rr;
      int vd = n * 16 + fr;
      u16 hh, ll;
      split2(acc[n][rr], hh, ll);
      size_t off = (rb + tt) * 2048 + h * 128 + vd;
      oh[off] = hh; ol[off] = ll;
    }
}

// ===========================================================================
extern "C" void kernel_launch(void* const* d_in, const int* in_sizes, int n_in,
                              void* d_out, int out_size, void* d_ws, size_t ws_size,
                              hipStream_t stream) {
  (void)in_sizes; (void)n_in; (void)out_size; (void)ws_size;
  const float* x  = (const float*)d_in[0];
  const float* Wq = (const float*)d_in[1];
  const float* Wk = (const float*)d_in[2];
  const float* Wv = (const float*)d_in[3];
  const float* gq = (const float*)d_in[4];
  const float* gk = (const float*)d_in[5];
  const float* gv = (const float*)d_in[6];
  const float* cq = (const float*)d_in[7];
  const float* ck = (const float*)d_in[8];
  const float* cv = (const float*)d_in[9];
  const float* Wa = (const float*)d_in[10];
  const float* Wb = (const float*)d_in[11];
  const float* Wo = (const float*)d_in[12];
  const float* Wg = (const float*)d_in[13];
  float* out = (float*)d_out;
  char* ws = (char*)d_ws;

  const size_t MiB = 1024 * 1024;
  // ---- workspace (peak exactly 256 MiB, liveness-audited) ----
  u16* Wqkv_h = (u16*)(ws + 0 * MiB);      // 8  ([4096][1024])
  u16* Wqkv_l = (u16*)(ws + 8 * MiB);      // 8
  u16* Wo_h   = (u16*)(ws + 16 * MiB);     // 4
  u16* Wo_l   = (u16*)(ws + 20 * MiB);     // 4
  u16* Wg_h   = (u16*)(ws + 24 * MiB);     // 2
  u16* Wg_l   = (u16*)(ws + 26 * MiB);     // 2
  float* gbuf = (float*)(ws + 28 * MiB);   // 0.5
  u16* x_h    = (u16*)(ws + 32 * MiB);     // 16  [dead after qkv gemm]
  u16* x_l    = (u16*)(ws + 48 * MiB);     // 16
  float* qkv  = (float*)(ws + 64 * MiB);   // 128 [dead after convs]
  u16* q_h = (u16*)(ws + 192 * MiB);       // 16
  u16* q_l = (u16*)(ws + 208 * MiB);       // 16
  u16* k_h = (u16*)(ws + 224 * MiB);       // 16
  u16* k_l = (u16*)(ws + 240 * MiB);       // 16 (ends at 256)
  u16* vg_h = (u16*)(ws + 32 * MiB);       // 32 (x pair dead)
  u16* vg_l = (u16*)d_out;                 // 32 (d_out scratch; dead after scan)
  u16* Sp_h = (u16*)(ws + 96 * MiB);       // 32 (qkv dead)
  u16* Sp_l = (u16*)(ws + 128 * MiB);      // 32
  u16* o_h  = (u16*)(ws + 64 * MiB);       // 32 (qkv head dead)
  u16* o_l  = (u16*)d_out;                 // 32 (vg_l dead after scan)
  u16* p_h  = (u16*)(ws + 96 * MiB);       // 16 (Sp_h dead after pass2)
  u16* p_l  = (u16*)(ws + 112 * MiB);      // 16 (Sp_h tail)

  dim3 blk(256);
  // casts + splits: 2 launches
  castx_gab<<<dim3(8192), blk, 0, stream>>>(x, x_h, x_l, Wa, Wb, gbuf);
  transcast_all<<<dim3(7168), blk, 0, stream>>>(Wq, Wk, Wv, Wo, Wg,
                                                Wqkv_h, Wqkv_l, Wo_h, Wo_l, Wg_h, Wg_l);
  // merged QKV projection: 256^2-tile 4-phase pipelined split GEMM (r12)
  gemm_sp_big<<<dim3(16, 32), dim3(512), 0, stream>>>(x_h, x_l, Wqkv_h, Wqkv_l, qkv, 8192, 4096, 1024);
  // fused zrms+conv+silu -> split pairs; q+k merged, v g-scaled
  conv_qk<<<dim3(16384), blk, 0, stream>>>(qkv, cq, ck, gq, gk, q_h, q_l, k_h, k_l);
  conv_fs<2048, 1><<<dim3(8192), dim3(512), 0, stream>>>(qkv + 2048, cv, gv, gbuf, vg_h, vg_l);
  // chunked recurrence
  scan_kernel<<<dim3(512), blk, 0, stream>>>(k_h, k_l, vg_h, vg_l, Sp_h, Sp_l);
  pass2_sp<<<dim3(2048), blk, 0, stream>>>(q_h, q_l, k_h, vg_h, Sp_h, Sp_l, o_h, o_l);
  // output projection (mid 2-phase, split pair out) + gated final GEMM
  gemm_sp_mid<1><<<dim3(4, 64), dim3(512), 0, stream>>>(o_h, o_l, Wo_h, Wo_l, nullptr, p_h, p_l, nullptr, nullptr, 8192, 1024, 2048);
  gemm_sp_mid<3><<<dim3(4, 64), dim3(512), 0, stream>>>(p_h, p_l, Wg_h, Wg_l, out, nullptr, nullptr, p_h, p_l, 8192, 1024, 1024);
}